// Round 1
// baseline (179.472 us; speedup 1.0000x reference)
//
#include <hip/hip_runtime.h>
#include <hip/hip_bf16.h>
#include <math.h>

using bf16x8 = __attribute__((ext_vector_type(8))) __bf16;
using f32x4  = __attribute__((ext_vector_type(4))) float;

#define B_SZ    8192
#define S_STEPS 51
#define M_ROWS  (B_SZ * S_STEPS)

__device__ __forceinline__ f32x4 mfma16(bf16x8 a, bf16x8 b, f32x4 c) {
    return __builtin_amdgcn_mfma_f32_16x16x32_bf16(a, b, c, 0, 0, 0);
}

// ---------------- quadrature constants (fp64, matches numpy) ----------------
__global__ void ccq_kernel(float* __restrict__ ccw, float* __restrict__ stp) {
    int s = threadIdx.x;
    if (s >= S_STEPS) return;
    double pi50 = M_PI / 50.0;
    double acc = 0.0;
    for (int j = 0; j <= 50; j += 2) {           // odd j have weight 0
        double wq = (j == 0) ? 1.0 : 2.0 / (1.0 - (double)(j * j));
        double m;
        if (s == 0) m = 0.5;                     // lam[:,0] = 0.5
        else if (s == 50) m = 0.5;               // 0.5*cos(j*pi), j even -> 0.5
        else m = cos((double)(j * s) * pi50);
        acc += m * wq;
    }
    ccw[s] = (float)(acc * (2.0 / 50.0));
    stp[s] = (float)cos((double)s * pi50);
}

// -------- pack fp32 weights (Ksrc x Nsrc row-major) into MFMA B-frag order --
// dst[((cg*KSTEPS+ks)*64 + lane)*8 + j] = W[k][col]
//   col = cg*16 + (lane&15), k = ks*32 + (lane>>4)*8 + j, zero-padded
__global__ void pack_weights(const float* __restrict__ src, __bf16* __restrict__ dst,
                             int Ksrc, int Nsrc, int KSTEPS, int CG) {
    int idx = blockIdx.x * 256 + threadIdx.x;
    int total = CG * KSTEPS * 512;
    if (idx >= total) return;
    int j    = idx & 7;
    int lane = (idx >> 3) & 63;
    int ks   = (idx >> 9) % KSTEPS;
    int cg   = (idx >> 9) / KSTEPS;
    int col = cg * 16 + (lane & 15);
    int k   = ks * 32 + (lane >> 4) * 8 + j;
    float v = (k < Ksrc && col < Nsrc) ? src[k * Nsrc + col] : 0.0f;
    dst[idx] = (__bf16)v;
}

// ---------------- fused MLP building blocks ----------------
// act LDS layout: 16B chunks, chunk index within row XOR-swizzled by (row&MASK)
// idx16(row, chunk) = row*CHUNKS + (chunk ^ (row & MASK))

template<int KSTEPS, int CHUNKS, int MASK>
__device__ __forceinline__ void gemm_layer(const __bf16* __restrict__ actIn,
                                           const __bf16* __restrict__ wpack,
                                           const float* __restrict__ bias,
                                           __bf16* __restrict__ actOut,
                                           int wid, int lane) {
    const bf16x8* wp = (const bf16x8*)wpack;
    f32x4 acc[4][4];
#pragma unroll
    for (int m = 0; m < 4; ++m)
#pragma unroll
        for (int n = 0; n < 4; ++n) acc[m][n] = (f32x4)0.0f;

    for (int ks = 0; ks < KSTEPS; ++ks) {
        bf16x8 af[4];
#pragma unroll
        for (int m = 0; m < 4; ++m) {
            int row   = m * 16 + (lane & 15);
            int chunk = ks * 4 + (lane >> 4);
            int idx16 = row * CHUNKS + (chunk ^ (row & MASK));
            af[m] = *(const bf16x8*)(actIn + idx16 * 8);
        }
        bf16x8 bf[4];
#pragma unroll
        for (int n = 0; n < 4; ++n) {
            int cg = wid * 4 + n;
            bf[n] = wp[(cg * KSTEPS + ks) * 64 + lane];
        }
#pragma unroll
        for (int m = 0; m < 4; ++m)
#pragma unroll
            for (int n = 0; n < 4; ++n)
                acc[m][n] = mfma16(af[m], bf[n], acc[m][n]);
    }
    // epilogue: bias + relu -> bf16 LDS (swizzled, CHUNKS=32/MASK=7 output)
#pragma unroll
    for (int n = 0; n < 4; ++n) {
        int col = (wid * 4 + n) * 16 + (lane & 15);
        float bv = bias[col];
#pragma unroll
        for (int m = 0; m < 4; ++m) {
#pragma unroll
            for (int r = 0; r < 4; ++r) {
                float v = acc[m][n][r] + bv;
                v = fmaxf(v, 0.0f);
                int row = m * 16 + (lane >> 4) * 4 + r;
                int idx = (row * 32 + ((col >> 3) ^ (row & 7))) * 8 + (col & 7);
                actOut[idx] = (__bf16)v;
            }
        }
    }
}

// final layer: K=256 (8 ksteps), N padded to 16; each wave does 16 rows
template<int MODE>
__device__ __forceinline__ void final_layer(const __bf16* __restrict__ actIn,
                                            const __bf16* __restrict__ wpack,
                                            const float* __restrict__ bias,
                                            float* __restrict__ out0,
                                            float* __restrict__ out1,
                                            int rb, int wid, int lane) {
    const bf16x8* wp = (const bf16x8*)wpack;
    f32x4 acc = (f32x4)0.0f;
    for (int ks = 0; ks < 8; ++ks) {
        int row   = wid * 16 + (lane & 15);
        int chunk = ks * 4 + (lane >> 4);
        bf16x8 af = *(const bf16x8*)(actIn + (row * 32 + (chunk ^ (row & 7))) * 8);
        acc = mfma16(af, wp[ks * 64 + lane], acc);
    }
    int col = lane & 15;
    if (MODE == 0) {
        if (col == 0) {
            float b = bias[0];
#pragma unroll
            for (int r = 0; r < 4; ++r) {
                int row = wid * 16 + (lane >> 4) * 4 + r;
                float v = acc[r] + b;
                out0[rb + row] = (v > 0.0f) ? (v + 1.0f) : expf(v);  // elu+1
            }
        }
    } else {
        if (col < 2) {
            float b = bias[col];
            float* dst = (col == 0) ? out0 : out1;
#pragma unroll
            for (int r = 0; r < 4; ++r) {
                int row = wid * 16 + (lane >> 4) * 4 + r;
                dst[rb + row] = acc[r] + b;
            }
        }
    }
}

// MODE 0: integrand net, rows = s*8192 + i, input [x*(step+1)/2, h(7)], out dz
// MODE 1: h-net, rows = i, input [h(7)], out (offset, log-scale)
template<int MODE>
__global__ __launch_bounds__(256) void mlp_kernel(
    const float* __restrict__ x, const float* __restrict__ h,
    const float* __restrict__ steps,
    const __bf16* __restrict__ w0p, const __bf16* __restrict__ w1p,
    const __bf16* __restrict__ w2p, const __bf16* __restrict__ w3p,
    const float* __restrict__ b0, const float* __restrict__ b1,
    const float* __restrict__ b2, const float* __restrict__ b3,
    float* __restrict__ out0, float* __restrict__ out1) {
    __shared__ __bf16 actA[64 * 256];
    __shared__ __bf16 actB[64 * 256];
    __bf16* zin = actB;  // 64x32 input tile aliases actB (free until layer 1)

    int tid  = threadIdx.x;
    int lane = tid & 63;
    int wid  = tid >> 6;
    int rb   = blockIdx.x * 64;

    // build padded input tile (64 rows x 32 cols, bf16, swizzled CHUNKS=4/MASK=3)
    {
        int row   = tid >> 2;
        int cpart = tid & 3;
        float vals[8];
        if (MODE == 0) {
            int s  = rb >> 13;
            int i  = (rb & (B_SZ - 1)) + row;
            float sc = (steps[s] + 1.0f) * 0.5f;
#pragma unroll
            for (int j = 0; j < 8; ++j) {
                int c = cpart * 8 + j;
                float v = 0.0f;
                if (c == 0) v = x[i] * sc;
                else if (c < 8) v = h[i * 7 + c - 1];
                vals[j] = v;
            }
        } else {
            int i = rb + row;
#pragma unroll
            for (int j = 0; j < 8; ++j) {
                int c = cpart * 8 + j;
                vals[j] = (c < 7) ? h[i * 7 + c] : 0.0f;
            }
        }
        bf16x8 zv;
#pragma unroll
        for (int j = 0; j < 8; ++j) zv[j] = (__bf16)vals[j];
        int zidx = (row * 4 + (cpart ^ (row & 3))) * 8;
        *(bf16x8*)(zin + zidx) = zv;
    }
    __syncthreads();

    gemm_layer<1, 4, 3>(zin, w0p, b0, actA, wid, lane);   // 32(pad) -> 256
    __syncthreads();
    gemm_layer<8, 32, 7>(actA, w1p, b1, actB, wid, lane); // 256 -> 256
    __syncthreads();
    gemm_layer<8, 32, 7>(actB, w2p, b2, actA, wid, lane); // 256 -> 256
    __syncthreads();
    final_layer<MODE>(actA, w3p, b3, out0, out1, rb, wid, lane);
}

// ---------------- final reduction ----------------
__global__ void reduce_kernel(const float* __restrict__ dz, const float* __restrict__ x,
                              const float* __restrict__ ho, const float* __restrict__ hs,
                              const float* __restrict__ ccw, float* __restrict__ out) {
    __shared__ float w[S_STEPS];
    int t = threadIdx.x;
    if (t < S_STEPS) w[t] = ccw[t];
    __syncthreads();
    int i = blockIdx.x * blockDim.x + t;
    float acc = 0.0f;
    for (int s = 0; s < S_STEPS; ++s) acc += dz[s * B_SZ + i] * w[s];
    float integral = acc * x[i] * 0.5f;
    out[i] = expf(hs[i]) * integral + ho[i];
}

extern "C" void kernel_launch(void* const* d_in, const int* in_sizes, int n_in,
                              void* d_out, int out_size, void* d_ws, size_t ws_size,
                              hipStream_t stream) {
    (void)in_sizes; (void)n_in; (void)out_size; (void)ws_size;
    const float* x = (const float*)d_in[0];
    const float* h = (const float*)d_in[1];
    const float* iW[4] = {(const float*)d_in[2], (const float*)d_in[4],
                          (const float*)d_in[6], (const float*)d_in[8]};
    const float* ib[4] = {(const float*)d_in[3], (const float*)d_in[5],
                          (const float*)d_in[7], (const float*)d_in[9]};
    const float* hW[4] = {(const float*)d_in[10], (const float*)d_in[12],
                          (const float*)d_in[14], (const float*)d_in[16]};
    const float* hb[4] = {(const float*)d_in[11], (const float*)d_in[13],
                          (const float*)d_in[15], (const float*)d_in[17]};

    size_t off = 0;
    auto alloc = [&](size_t bytes) -> void* {
        void* p = (char*)d_ws + off;
        off += (bytes + 255) & ~(size_t)255;
        return p;
    };
    float*  dz   = (float*)alloc((size_t)M_ROWS * 4);
    float*  ho   = (float*)alloc(B_SZ * 4);
    float*  hs   = (float*)alloc(B_SZ * 4);
    float*  ccw  = (float*)alloc(64 * 4);
    float*  stp  = (float*)alloc(64 * 4);
    __bf16* iW0p = (__bf16*)alloc(16 * 1 * 512 * 2);
    __bf16* iW1p = (__bf16*)alloc(16 * 8 * 512 * 2);
    __bf16* iW2p = (__bf16*)alloc(16 * 8 * 512 * 2);
    __bf16* iW3p = (__bf16*)alloc(1 * 8 * 512 * 2);
    __bf16* hW0p = (__bf16*)alloc(16 * 1 * 512 * 2);
    __bf16* hW1p = (__bf16*)alloc(16 * 8 * 512 * 2);
    __bf16* hW2p = (__bf16*)alloc(16 * 8 * 512 * 2);
    __bf16* hW3p = (__bf16*)alloc(1 * 8 * 512 * 2);

    ccq_kernel<<<1, 64, 0, stream>>>(ccw, stp);

    auto pack = [&](const float* src, __bf16* dst, int Ks, int Ns, int KST, int CG) {
        int total = CG * KST * 512;
        pack_weights<<<(total + 255) / 256, 256, 0, stream>>>(src, dst, Ks, Ns, KST, CG);
    };
    pack(iW[0], iW0p, 8, 256, 1, 16);
    pack(iW[1], iW1p, 256, 256, 8, 16);
    pack(iW[2], iW2p, 256, 256, 8, 16);
    pack(iW[3], iW3p, 256, 1, 8, 1);
    pack(hW[0], hW0p, 7, 256, 1, 16);
    pack(hW[1], hW1p, 256, 256, 8, 16);
    pack(hW[2], hW2p, 256, 256, 8, 16);
    pack(hW[3], hW3p, 256, 2, 8, 1);

    mlp_kernel<0><<<M_ROWS / 64, 256, 0, stream>>>(
        x, h, stp, iW0p, iW1p, iW2p, iW3p, ib[0], ib[1], ib[2], ib[3], dz, dz);
    mlp_kernel<1><<<B_SZ / 64, 256, 0, stream>>>(
        x, h, stp, hW0p, hW1p, hW2p, hW3p, hb[0], hb[1], hb[2], hb[3], ho, hs);

    reduce_kernel<<<B_SZ / 256, 256, 0, stream>>>(dz, x, ho, hs, ccw, (float*)d_out);
}

// Round 2
// 153.299 us; speedup vs baseline: 1.1707x; 1.1707x over previous
//
#include <hip/hip_runtime.h>
#include <hip/hip_bf16.h>
#include <math.h>

using bf16x8 = __attribute__((ext_vector_type(8))) __bf16;
using f32x4  = __attribute__((ext_vector_type(4))) float;

#define B_SZ    8192
#define S_STEPS 51
#define M_ROWS  (B_SZ * S_STEPS)

__device__ __forceinline__ f32x4 mfma16(bf16x8 a, bf16x8 b, f32x4 c) {
    return __builtin_amdgcn_mfma_f32_16x16x32_bf16(a, b, c, 0, 0, 0);
}

// ---------------- quadrature constants (fp64, matches numpy) ----------------
__global__ void ccq_kernel(float* __restrict__ ccw, float* __restrict__ stp) {
    int s = threadIdx.x;
    if (s >= S_STEPS) return;
    double pi50 = M_PI / 50.0;
    double acc = 0.0;
    for (int j = 0; j <= 50; j += 2) {           // odd j have weight 0
        double wq = (j == 0) ? 1.0 : 2.0 / (1.0 - (double)(j * j));
        double m;
        if (s == 0) m = 0.5;
        else if (s == 50) m = 0.5;               // 0.5*cos(j*pi), j even -> 0.5
        else m = cos((double)(j * s) * pi50);
        acc += m * wq;
    }
    ccw[s] = (float)(acc * (2.0 / 50.0));
    stp[s] = (float)cos((double)s * pi50);
}

// -------- pack fp32 weights (Ksrc x Nsrc row-major) into MFMA B-frag order --
// dst[((cg*KSTEPS+ks)*64 + lane)*8 + j] = W[k][col]
//   col = cg*16 + (lane&15), k = ks*32 + (lane>>4)*8 + j, zero-padded
// All 8 matrices in one launch.
struct PackArgs {
    const float* src[8];
    __hip_bfloat16* dst[8];
    int Ks[8], Ns[8], KST[8];
    int prefix[9];   // element-count prefix sums
};

__global__ void pack_all(PackArgs pa) {
    int idx = blockIdx.x * 256 + threadIdx.x;
    if (idx >= pa.prefix[8]) return;
    int m = 0;
    while (idx >= pa.prefix[m + 1]) ++m;
    int e = idx - pa.prefix[m];
    int KSTEPS = pa.KST[m];
    int j    = e & 7;
    int lane = (e >> 3) & 63;
    int ks   = (e >> 9) % KSTEPS;
    int cg   = (e >> 9) / KSTEPS;
    int col = cg * 16 + (lane & 15);
    int k   = ks * 32 + (lane >> 4) * 8 + j;
    float v = (k < pa.Ks[m] && col < pa.Ns[m]) ? pa.src[m][k * pa.Ns[m] + col] : 0.0f;
    ((__bf16*)pa.dst[m])[e] = (__bf16)v;
}

// ---------------- fused MLP building blocks ----------------
// act LDS layout: 16B chunks, chunk index within row XOR-swizzled by (row&MASK)
// idx16(row, chunk) = row*CHUNKS + (chunk ^ (row & MASK))

// NF = col-fragments per wave (8 waves x NF=2 -> 256 cols)
template<int KSTEPS, int CHUNKS, int MASK, int NF>
__device__ __forceinline__ void gemm_layer(const __bf16* __restrict__ actIn,
                                           const __bf16* __restrict__ wpack,
                                           const float* __restrict__ bias,
                                           __bf16* __restrict__ actOut,
                                           int wid, int lane) {
    const bf16x8* wp = (const bf16x8*)wpack;
    f32x4 acc[4][NF];
#pragma unroll
    for (int m = 0; m < 4; ++m)
#pragma unroll
        for (int n = 0; n < NF; ++n) acc[m][n] = (f32x4)0.0f;

    for (int ks = 0; ks < KSTEPS; ++ks) {
        bf16x8 af[4];
#pragma unroll
        for (int m = 0; m < 4; ++m) {
            int row   = m * 16 + (lane & 15);
            int chunk = ks * 4 + (lane >> 4);
            int idx16 = row * CHUNKS + (chunk ^ (row & MASK));
            af[m] = *(const bf16x8*)(actIn + idx16 * 8);
        }
        bf16x8 bf[NF];
#pragma unroll
        for (int n = 0; n < NF; ++n) {
            int cg = wid * NF + n;
            bf[n] = wp[(cg * KSTEPS + ks) * 64 + lane];
        }
#pragma unroll
        for (int m = 0; m < 4; ++m)
#pragma unroll
            for (int n = 0; n < NF; ++n)
                acc[m][n] = mfma16(af[m], bf[n], acc[m][n]);
    }
    // epilogue: bias + relu -> bf16 LDS (swizzled, CHUNKS=32/MASK=7 output)
#pragma unroll
    for (int n = 0; n < NF; ++n) {
        int col = (wid * NF + n) * 16 + (lane & 15);
        float bv = bias[col];
#pragma unroll
        for (int m = 0; m < 4; ++m) {
#pragma unroll
            for (int r = 0; r < 4; ++r) {
                float v = acc[m][n][r] + bv;
                v = fmaxf(v, 0.0f);
                int row = m * 16 + (lane >> 4) * 4 + r;
                int idx = (row * 32 + ((col >> 3) ^ (row & 7))) * 8 + (col & 7);
                actOut[idx] = (__bf16)v;
            }
        }
    }
}

// final layer: K=256 (8 ksteps), N padded to 16; waves 0-3 do 16 rows each
template<int MODE>
__device__ __forceinline__ void final_layer(const __bf16* __restrict__ actIn,
                                            const __bf16* __restrict__ wpack,
                                            const float* __restrict__ bias,
                                            float* __restrict__ out0,
                                            float* __restrict__ out1,
                                            int rb, int wid, int lane) {
    const bf16x8* wp = (const bf16x8*)wpack;
    f32x4 acc = (f32x4)0.0f;
    for (int ks = 0; ks < 8; ++ks) {
        int row   = wid * 16 + (lane & 15);
        int chunk = ks * 4 + (lane >> 4);
        bf16x8 af = *(const bf16x8*)(actIn + (row * 32 + (chunk ^ (row & 7))) * 8);
        acc = mfma16(af, wp[ks * 64 + lane], acc);
    }
    int col = lane & 15;
    if (MODE == 0) {
        if (col == 0) {
            float b = bias[0];
#pragma unroll
            for (int r = 0; r < 4; ++r) {
                int row = wid * 16 + (lane >> 4) * 4 + r;
                float v = acc[r] + b;
                out0[rb + row] = (v > 0.0f) ? (v + 1.0f) : expf(v);  // elu+1
            }
        }
    } else {
        if (col < 2) {
            float b = bias[col];
            float* dst = (col == 0) ? out0 : out1;
#pragma unroll
            for (int r = 0; r < 4; ++r) {
                int row = wid * 16 + (lane >> 4) * 4 + r;
                dst[rb + row] = acc[r] + b;
            }
        }
    }
}

// MODE 0: integrand net, rows = s*8192 + i, input [x*(step+1)/2, h(7)], out dz
// MODE 1: h-net, rows = i, input [h(7)], out (offset, log-scale)
template<int MODE>
__global__ __launch_bounds__(512, 4) void mlp_kernel(
    const float* __restrict__ x, const float* __restrict__ h,
    const float* __restrict__ steps,
    const __bf16* __restrict__ w0p, const __bf16* __restrict__ w1p,
    const __bf16* __restrict__ w2p, const __bf16* __restrict__ w3p,
    const float* __restrict__ b0, const float* __restrict__ b1,
    const float* __restrict__ b2, const float* __restrict__ b3,
    float* __restrict__ out0, float* __restrict__ out1) {
    __shared__ __bf16 actA[64 * 256];
    __shared__ __bf16 actB[64 * 256];
    __bf16* zin = actB;  // 64x32 input tile aliases actB (free until layer 1)

    int tid  = threadIdx.x;
    int lane = tid & 63;
    int wid  = tid >> 6;
    int rb   = blockIdx.x * 64;

    // build padded input tile (64 rows x 32 cols, bf16, swizzled CHUNKS=4/MASK=3)
    if (tid < 256) {
        int row   = tid >> 2;
        int cpart = tid & 3;
        float vals[8];
        if (MODE == 0) {
            int s  = rb >> 13;
            int i  = (rb & (B_SZ - 1)) + row;
            float sc = (steps[s] + 1.0f) * 0.5f;
#pragma unroll
            for (int j = 0; j < 8; ++j) {
                int c = cpart * 8 + j;
                float v = 0.0f;
                if (c == 0) v = x[i] * sc;
                else if (c < 8) v = h[i * 7 + c - 1];
                vals[j] = v;
            }
        } else {
            int i = rb + row;
#pragma unroll
            for (int j = 0; j < 8; ++j) {
                int c = cpart * 8 + j;
                vals[j] = (c < 7) ? h[i * 7 + c] : 0.0f;
            }
        }
        bf16x8 zv;
#pragma unroll
        for (int j = 0; j < 8; ++j) zv[j] = (__bf16)vals[j];
        int zidx = (row * 4 + (cpart ^ (row & 3))) * 8;
        *(bf16x8*)(zin + zidx) = zv;
    }
    __syncthreads();

    gemm_layer<1, 4, 3, 2>(zin, w0p, b0, actA, wid, lane);   // 32(pad) -> 256
    __syncthreads();
    gemm_layer<8, 32, 7, 2>(actA, w1p, b1, actB, wid, lane); // 256 -> 256
    __syncthreads();
    gemm_layer<8, 32, 7, 2>(actB, w2p, b2, actA, wid, lane); // 256 -> 256
    __syncthreads();
    if (wid < 4)
        final_layer<MODE>(actA, w3p, b3, out0, out1, rb, wid, lane);
}

// ---------------- final reduction ----------------
__global__ void reduce_kernel(const float* __restrict__ dz, const float* __restrict__ x,
                              const float* __restrict__ ho, const float* __restrict__ hs,
                              const float* __restrict__ ccw, float* __restrict__ out) {
    __shared__ float w[S_STEPS];
    int t = threadIdx.x;
    if (t < S_STEPS) w[t] = ccw[t];
    __syncthreads();
    int i = blockIdx.x * blockDim.x + t;
    float acc = 0.0f;
    for (int s = 0; s < S_STEPS; ++s) acc += dz[s * B_SZ + i] * w[s];
    float integral = acc * x[i] * 0.5f;
    out[i] = expf(hs[i]) * integral + ho[i];
}

extern "C" void kernel_launch(void* const* d_in, const int* in_sizes, int n_in,
                              void* d_out, int out_size, void* d_ws, size_t ws_size,
                              hipStream_t stream) {
    (void)in_sizes; (void)n_in; (void)out_size; (void)ws_size;
    const float* x = (const float*)d_in[0];
    const float* h = (const float*)d_in[1];
    const float* iW[4] = {(const float*)d_in[2], (const float*)d_in[4],
                          (const float*)d_in[6], (const float*)d_in[8]};
    const float* ib[4] = {(const float*)d_in[3], (const float*)d_in[5],
                          (const float*)d_in[7], (const float*)d_in[9]};
    const float* hW[4] = {(const float*)d_in[10], (const float*)d_in[12],
                          (const float*)d_in[14], (const float*)d_in[16]};
    const float* hb[4] = {(const float*)d_in[11], (const float*)d_in[13],
                          (const float*)d_in[15], (const float*)d_in[17]};

    size_t off = 0;
    auto alloc = [&](size_t bytes) -> void* {
        void* p = (char*)d_ws + off;
        off += (bytes + 255) & ~(size_t)255;
        return p;
    };
    float*  dz   = (float*)alloc((size_t)M_ROWS * 4);
    float*  ho   = (float*)alloc(B_SZ * 4);
    float*  hs   = (float*)alloc(B_SZ * 4);
    float*  ccw  = (float*)alloc(64 * 4);
    float*  stp  = (float*)alloc(64 * 4);
    __bf16* iW0p = (__bf16*)alloc(16 * 1 * 512 * 2);
    __bf16* iW1p = (__bf16*)alloc(16 * 8 * 512 * 2);
    __bf16* iW2p = (__bf16*)alloc(16 * 8 * 512 * 2);
    __bf16* iW3p = (__bf16*)alloc(1 * 8 * 512 * 2);
    __bf16* hW0p = (__bf16*)alloc(16 * 1 * 512 * 2);
    __bf16* hW1p = (__bf16*)alloc(16 * 8 * 512 * 2);
    __bf16* hW2p = (__bf16*)alloc(16 * 8 * 512 * 2);
    __bf16* hW3p = (__bf16*)alloc(1 * 8 * 512 * 2);

    ccq_kernel<<<1, 64, 0, stream>>>(ccw, stp);

    PackArgs pa;
    const float* srcs[8] = {iW[0], iW[1], iW[2], iW[3], hW[0], hW[1], hW[2], hW[3]};
    __bf16*      dsts[8] = {iW0p, iW1p, iW2p, iW3p, hW0p, hW1p, hW2p, hW3p};
    int Ks[8]  = {8, 256, 256, 256, 7, 256, 256, 256};
    int Ns[8]  = {256, 256, 256, 1, 256, 256, 256, 2};
    int KST[8] = {1, 8, 8, 8, 1, 8, 8, 8};
    int CG[8]  = {16, 16, 16, 1, 16, 16, 16, 1};
    int pfx = 0;
    for (int m = 0; m < 8; ++m) {
        pa.src[m] = srcs[m];
        pa.dst[m] = (__hip_bfloat16*)dsts[m];
        pa.Ks[m] = Ks[m]; pa.Ns[m] = Ns[m]; pa.KST[m] = KST[m];
        pa.prefix[m] = pfx;
        pfx += CG[m] * KST[m] * 512;
    }
    pa.prefix[8] = pfx;
    pack_all<<<(pfx + 255) / 256, 256, 0, stream>>>(pa);

    mlp_kernel<0><<<M_ROWS / 64, 512, 0, stream>>>(
        x, h, stp, iW0p, iW1p, iW2p, iW3p, ib[0], ib[1], ib[2], ib[3], dz, dz);
    mlp_kernel<1><<<B_SZ / 64, 512, 0, stream>>>(
        x, h, stp, hW0p, hW1p, hW2p, hW3p, hb[0], hb[1], hb[2], hb[3], ho, hs);

    reduce_kernel<<<B_SZ / 256, 256, 0, stream>>>(dz, x, ho, hs, ccw, (float*)d_out);
}